// Round 7
// baseline (433.677 us; speedup 1.0000x reference)
//
#include <hip/hip_runtime.h>

#define F 128
#define NGRAPH 512

typedef __attribute__((ext_vector_type(8))) __bf16 bf16x8;
typedef __attribute__((ext_vector_type(4))) float f32x4;
typedef __attribute__((ext_vector_type(8))) unsigned short u16x8;

// ---- bf16 helpers (RTNE) ----
__device__ __forceinline__ unsigned short f2bf(float f) {
    unsigned int u = __float_as_uint(f);
    u = (u + 0x7fffu + ((u >> 16) & 1u)) >> 16;
    return (unsigned short)u;
}
__device__ __forceinline__ float bf2f(unsigned short b) {
    return __uint_as_float(((unsigned int)b) << 16);
}

// ---------------- CSR build ----------------

__global__ __launch_bounds__(256) void k_hist(const int* __restrict__ dst,
                                              int* __restrict__ counts, int e) {
    int i = blockIdx.x * 256 + threadIdx.x;
    if (i < e) atomicAdd(&counts[dst[i]], 1);
}

__global__ __launch_bounds__(256) void k_bsum(const int* __restrict__ counts,
                                              int* __restrict__ bsum, int n) {
    __shared__ int sm[256];
    const int t = threadIdx.x;
    int i = blockIdx.x * 256 + t;
    sm[t] = (i < n) ? counts[i] : 0;
    __syncthreads();
    for (int off = 128; off > 0; off >>= 1) {
        if (t < off) sm[t] += sm[t + off];
        __syncthreads();
    }
    if (t == 0) bsum[blockIdx.x] = sm[0];
}

__global__ __launch_bounds__(256) void k_scanb(const int* __restrict__ bsum,
                                               int* __restrict__ boff, int nb,
                                               int* __restrict__ rs, int n) {
    __shared__ int sm[256];
    const int t = threadIdx.x;
    const int npt = (nb + 255) >> 8;
    const int base = t * npt;
    int s = 0;
    for (int i = 0; i < npt; i++) { int idx = base + i; if (idx < nb) s += bsum[idx]; }
    sm[t] = s;
    __syncthreads();
    for (int off = 1; off < 256; off <<= 1) {
        int u = (t >= off) ? sm[t - off] : 0;
        __syncthreads();
        sm[t] += u;
        __syncthreads();
    }
    int run = (t == 0) ? 0 : sm[t - 1];
    for (int i = 0; i < npt; i++) {
        int idx = base + i;
        if (idx < nb) { boff[idx] = run; run += bsum[idx]; }
    }
    if (t == 255) rs[n] = sm[255];
}

__global__ __launch_bounds__(256) void k_apply(const int* __restrict__ counts,
                                               const int* __restrict__ boff,
                                               int* __restrict__ rs,
                                               int* __restrict__ cursor, int n) {
    __shared__ int sm[256];
    const int t = threadIdx.x;
    int i = blockIdx.x * 256 + t;
    int v = (i < n) ? counts[i] : 0;
    sm[t] = v;
    __syncthreads();
    for (int off = 1; off < 256; off <<= 1) {
        int u = (t >= off) ? sm[t - off] : 0;
        __syncthreads();
        sm[t] += u;
        __syncthreads();
    }
    int excl = sm[t] - v + boff[blockIdx.x];
    if (i < n) { rs[i] = excl; cursor[i] = excl; }
}

__global__ __launch_bounds__(256) void k_scatter(const int* __restrict__ src,
                                                 const int* __restrict__ dst,
                                                 int* __restrict__ cursor,
                                                 int* __restrict__ csr, int e) {
    int i = blockIdx.x * 256 + threadIdx.x;
    if (i < e) {
        int p = atomicAdd(&cursor[dst[i]], 1);
        csr[p] = src[i];
    }
}

__global__ void k_gbounds(const int* __restrict__ batch, int* __restrict__ gstart,
                          int n, int ng) {
    int g = blockIdx.x * blockDim.x + threadIdx.x;
    if (g > ng) return;
    if (g == ng) { gstart[ng] = n; return; }
    int lo = 0, hi = n;
    while (lo < hi) {
        int mid = (lo + hi) >> 1;
        if (batch[mid] < g) lo = mid + 1; else hi = mid;
    }
    gstart[g] = lo;
}

// ---------------- weight prep: 3 layers, fp32 -> bf16 hi/lo, frag-major ----------------

__global__ __launch_bounds__(256) void k_wprep3(
    const float* __restrict__ W1l, const float* __restrict__ W1r,
    const float* __restrict__ W2l, const float* __restrict__ W2r,
    const float* __restrict__ W3l, const float* __restrict__ W3r,
    unsigned short* __restrict__ whi, unsigned short* __restrict__ wlo) {
    int tid = blockIdx.x * 256 + threadIdx.x;   // 0 .. 98303
    if (tid >= 3 * 32768) return;
    int layer = tid >> 15;
    int t = tid & 32767;
    const float* Wl = (layer == 0) ? W1l : ((layer == 1) ? W2l : W3l);
    const float* Wr = (layer == 0) ? W1r : ((layer == 1) ? W2r : W3r);
    int j = t & 7;
    int fp = t >> 3;
    int l = fp & 63;
    int ks = (fp >> 6) & 7;
    int nt = fp >> 9;
    int k = ks * 32 + ((l >> 4) << 3) + j;
    int n = nt * 16 + (l & 15);
    float v = (k < F) ? Wl[k * F + n] : Wr[(k - F) * F + n];
    unsigned short hi = f2bf(v);
    unsigned short lo = f2bf(v - bf2f(hi));
    whi[tid] = hi;
    wlo[tid] = lo;
}

// ---------------- x prep: fp32 -> bf16 hi/lo ----------------

__global__ __launch_bounds__(256) void k_xprep(const float4* __restrict__ x4,
                                               unsigned short* __restrict__ hi,
                                               unsigned short* __restrict__ lo, int n4) {
    int i = blockIdx.x * 256 + threadIdx.x;
    if (i >= n4) return;
    float4 v = x4[i];
    ushort4 h, l;
    h.x = f2bf(v.x); l.x = f2bf(v.x - bf2f(h.x));
    h.y = f2bf(v.y); l.y = f2bf(v.y - bf2f(h.y));
    h.z = f2bf(v.z); l.z = f2bf(v.z - bf2f(h.z));
    h.w = f2bf(v.w); l.w = f2bf(v.w - bf2f(h.w));
    *(ushort4*)&hi[i * 4] = h;
    *(ushort4*)&lo[i * 4] = l;
}

// ---------------- fused SAGE layer: O = relu([mean_nbr(H) | H] @ [Wl;Wr] + bias) ----
// Staging gathers neighbors directly from Hhi (CSR) — no separate agg pass.
// K = 256; split-bf16 3-pass MFMA: Ahi@Whi + Ahi@Wlo + Alo@Whi.
// Block: 256 threads (4 waves), 64 rows x 128 cols; LDS XOR-swizzled at 8-elem grain.
// NOLO=1 skips the O-lo store (layer 3: lo never consumed downstream).

template <int NOLO>
__global__ __launch_bounds__(256, 2) void k_sage(
    const unsigned short* __restrict__ Hhi, const unsigned short* __restrict__ Hlo,
    const int* __restrict__ rs, const int* __restrict__ csr,
    const unsigned short* __restrict__ whi, const unsigned short* __restrict__ wlo,
    const float* __restrict__ bias,
    unsigned short* __restrict__ Ohi, unsigned short* __restrict__ Olo, int nrows)
{
    __shared__ unsigned short ahi[64 * 256];
    __shared__ unsigned short alo[64 * 256];
    const int t = threadIdx.x;
    const int row0 = blockIdx.x * 64;
    const u16x8* H8h = (const u16x8*)Hhi;
    const u16x8* H8l = (const u16x8*)Hlo;

    // ---- stage self part: chunks 16..31 of each row (coalesced copies) ----
#pragma unroll
    for (int it = 0; it < 4; it++) {
        int i = t + 256 * it;          // 0..1023
        int row = i >> 4;              // 0..63
        int cc = i & 15;               // 0..15
        int gn = row0 + row;
        u16x8 vh = (u16x8)0, vl = (u16x8)0;
        if (gn < nrows) { vh = H8h[gn * 16 + cc]; vl = H8l[gn * 16 + cc]; }
        int didx = row * 256 + (((16 + cc) * 8) ^ ((row & 7) << 3));
        *(u16x8*)&ahi[didx] = vh;
        *(u16x8*)&alo[didx] = vl;
    }

    // ---- stage agg part: chunks 0..15 = mean over CSR neighbors (gather) ----
#pragma unroll
    for (int it = 0; it < 4; it++) {
        int i = t + 256 * it;
        int row = i >> 4;
        int cc = i & 15;
        int gn = row0 + row;
        int e0 = 0, e1 = 0;
        if (gn < nrows) { e0 = rs[gn]; e1 = rs[gn + 1]; }
        float s0[8] = {}, s1[8] = {}, s2[8] = {}, s3[8] = {};
        int e = e0;
        for (; e + 4 <= e1; e += 4) {
            int a = csr[e], b = csr[e + 1], c2 = csr[e + 2], d = csr[e + 3];
            u16x8 va = H8h[a * 16 + cc];
            u16x8 vb = H8h[b * 16 + cc];
            u16x8 vc = H8h[c2 * 16 + cc];
            u16x8 vd = H8h[d * 16 + cc];
#pragma unroll
            for (int j = 0; j < 8; j++) {
                s0[j] += bf2f(va[j]);
                s1[j] += bf2f(vb[j]);
                s2[j] += bf2f(vc[j]);
                s3[j] += bf2f(vd[j]);
            }
        }
        for (; e < e1; e++) {
            u16x8 va = H8h[csr[e] * 16 + cc];
#pragma unroll
            for (int j = 0; j < 8; j++) s0[j] += bf2f(va[j]);
        }
        const float inv = 1.f / (float)max(e1 - e0, 1);
        u16x8 hi8, lo8;
#pragma unroll
        for (int j = 0; j < 8; j++) {
            float m = (s0[j] + s1[j] + s2[j] + s3[j]) * inv;
            unsigned short h = f2bf(m);
            hi8[j] = h;
            lo8[j] = f2bf(m - bf2f(h));
        }
        int didx = row * 256 + ((cc * 8) ^ ((row & 7) << 3));
        *(u16x8*)&ahi[didx] = hi8;
        *(u16x8*)&alo[didx] = lo8;
    }
    __syncthreads();

    // ---- MFMA: 3-pass split-bf16 ----
    const int w = t >> 6;
    const int l = t & 63;
    const int lm = l & 15;
    const int lk = l >> 4;
    const bf16x8* whiv = (const bf16x8*)whi;
    const bf16x8* wlov = (const bf16x8*)wlo;

    f32x4 acc[4][2];
#pragma unroll
    for (int rt = 0; rt < 4; rt++)
#pragma unroll
        for (int j = 0; j < 2; j++) acc[rt][j] = (f32x4)(0.f);

    for (int ks = 0; ks < 8; ks++) {
        const int kidx = ks * 32 + lk * 8;
        bf16x8 ah[4], al[4];
#pragma unroll
        for (int rt = 0; rt < 4; rt++) {
            int row = rt * 16 + lm;
            int idx = row * 256 + (kidx ^ ((row & 7) << 3));
            ah[rt] = *(const bf16x8*)&ahi[idx];
            al[rt] = *(const bf16x8*)&alo[idx];
        }
#pragma unroll
        for (int j = 0; j < 2; j++) {
            int nt = 2 * w + j;
            bf16x8 wh = whiv[(nt * 8 + ks) * 64 + l];
            bf16x8 wl = wlov[(nt * 8 + ks) * 64 + l];
#pragma unroll
            for (int rt = 0; rt < 4; rt++) {
                acc[rt][j] = __builtin_amdgcn_mfma_f32_16x16x32_bf16(ah[rt], wh, acc[rt][j], 0, 0, 0);
                acc[rt][j] = __builtin_amdgcn_mfma_f32_16x16x32_bf16(ah[rt], wl, acc[rt][j], 0, 0, 0);
                acc[rt][j] = __builtin_amdgcn_mfma_f32_16x16x32_bf16(al[rt], wh, acc[rt][j], 0, 0, 0);
            }
        }
    }

    // ---- epilogue: + bias, relu, split bf16 hi/lo, store ----
#pragma unroll
    for (int j = 0; j < 2; j++) {
        int col = (2 * w + j) * 16 + lm;
        float bv = bias[col];
#pragma unroll
        for (int rt = 0; rt < 4; rt++) {
#pragma unroll
            for (int r = 0; r < 4; r++) {
                int row = row0 + rt * 16 + lk * 4 + r;
                if (row < nrows) {
                    float v = fmaxf(acc[rt][j][r] + bv, 0.f);
                    unsigned short h = f2bf(v);
                    Ohi[(size_t)row * F + col] = h;
                    if (!NOLO) Olo[(size_t)row * F + col] = f2bf(v - bf2f(h));
                }
            }
        }
    }
}

// ---------------- standalone aggregation (layer 4): agg[v] = mean_e h[csr[e]] ----------------

template <int WRITELO>
__global__ __launch_bounds__(256) void k_aggm_bf(
    const unsigned short* __restrict__ hbf, const int* __restrict__ rs,
    const int* __restrict__ csr,
    unsigned short* __restrict__ agghi, unsigned short* __restrict__ agglo, int nnodes)
{
    int v = blockIdx.x * 16 + (threadIdx.x >> 4);
    if (v >= nnodes) return;
    int c = threadIdx.x & 15;
    const u16x8* h8 = (const u16x8*)hbf;
    int e0 = rs[v], e1 = rs[v + 1];

    float s0[8] = {}, s1[8] = {}, s2[8] = {}, s3[8] = {};
    int e = e0;
    for (; e + 4 <= e1; e += 4) {
        int a = csr[e], b = csr[e + 1], c2 = csr[e + 2], d = csr[e + 3];
        u16x8 va = h8[a * 16 + c];
        u16x8 vb = h8[b * 16 + c];
        u16x8 vc = h8[c2 * 16 + c];
        u16x8 vd = h8[d * 16 + c];
#pragma unroll
        for (int j = 0; j < 8; j++) {
            s0[j] += bf2f(va[j]);
            s1[j] += bf2f(vb[j]);
            s2[j] += bf2f(vc[j]);
            s3[j] += bf2f(vd[j]);
        }
    }
    for (; e < e1; e++) {
        u16x8 va = h8[csr[e] * 16 + c];
#pragma unroll
        for (int j = 0; j < 8; j++) s0[j] += bf2f(va[j]);
    }
    const float inv = 1.f / (float)max(e1 - e0, 1);
    u16x8 hi8, lo8;
#pragma unroll
    for (int j = 0; j < 8; j++) {
        float m = (s0[j] + s1[j] + s2[j] + s3[j]) * inv;
        unsigned short h = f2bf(m);
        hi8[j] = h;
        lo8[j] = f2bf(m - bf2f(h));
    }
    ((u16x8*)agghi)[v * 16 + c] = hi8;
    if (WRITELO) ((u16x8*)agglo)[v * 16 + c] = lo8;
}

// ---------------- per-graph mean pool (reads bf16 hi arrays) ----------------

__global__ void k_pool(const unsigned short* __restrict__ tagg,
                       const unsigned short* __restrict__ h3,
                       const int* __restrict__ gstart,
                       float* __restrict__ ps1, float* __restrict__ ps2)
{
    int g = blockIdx.x, c = threadIdx.x;  // 128 threads
    int v0 = gstart[g], v1 = gstart[g + 1];
    float s1 = 0.f, s2 = 0.f;
    for (int v = v0; v < v1; v++) {
        s1 += bf2f(tagg[(size_t)v * F + c]);
        s2 += bf2f(h3[(size_t)v * F + c]);
    }
    float inv = 1.f / (float)max(v1 - v0, 1);
    ps1[g * F + c] = s1 * inv;
    ps2[g * F + c] = s2 * inv;
}

// ---------------- final tiny GEMM ----------------

__global__ void k_final(const float* __restrict__ ps1, const float* __restrict__ ps2,
                        const float* __restrict__ W4l, const float* __restrict__ W4r,
                        const float* __restrict__ b4, float* __restrict__ out, int ngraph)
{
    int g = blockIdx.x * 4 + (threadIdx.x >> 6);
    int lane = threadIdx.x & 63;
    if (g >= ngraph) return;
    int k0 = lane * 2;
    float a0 = ps1[g * F + k0], a1 = ps1[g * F + k0 + 1];
    float c0v = ps2[g * F + k0], c1v = ps2[g * F + k0 + 1];
    float p0 = a0 * W4l[k0 * 2 + 0] + a1 * W4l[(k0 + 1) * 2 + 0] +
               c0v * W4r[k0 * 2 + 0] + c1v * W4r[(k0 + 1) * 2 + 0];
    float p1 = a0 * W4l[k0 * 2 + 1] + a1 * W4l[(k0 + 1) * 2 + 1] +
               c0v * W4r[k0 * 2 + 1] + c1v * W4r[(k0 + 1) * 2 + 1];
#pragma unroll
    for (int off = 32; off > 0; off >>= 1) {
        p0 += __shfl_down(p0, off);
        p1 += __shfl_down(p1, off);
    }
    if (lane == 0) {
        out[g * 2 + 0] = p0 + b4[0];
        out[g * 2 + 1] = p1 + b4[1];
    }
}

// ---------------- launcher ----------------

extern "C" void kernel_launch(void* const* d_in, const int* in_sizes, int n_in,
                              void* d_out, int out_size, void* d_ws, size_t ws_size,
                              hipStream_t stream)
{
    (void)n_in; (void)out_size; (void)ws_size;
    const float* x    = (const float*)d_in[0];
    const int*   ei   = (const int*)d_in[1];
    const int*   batch= (const int*)d_in[2];
    const float* W1l = (const float*)d_in[3];
    const float* W1r = (const float*)d_in[4];
    const float* b1  = (const float*)d_in[5];
    const float* W2l = (const float*)d_in[6];
    const float* W2r = (const float*)d_in[7];
    const float* b2  = (const float*)d_in[8];
    const float* W3l = (const float*)d_in[9];
    const float* W3r = (const float*)d_in[10];
    const float* b3  = (const float*)d_in[11];
    const float* W4l = (const float*)d_in[12];
    const float* W4r = (const float*)d_in[13];
    const float* b4  = (const float*)d_in[14];
    float* out = (float*)d_out;

    const int N = in_sizes[0] / F;   // 50000
    const int E = in_sizes[1] / 2;   // 600000
    const int NG = NGRAPH;
    const int* src = ei;
    const int* dst = ei + E;
    const int NB = (N + 255) / 256;
    const int EB = (E + 255) / 256;

    char* p = (char*)d_ws;
    auto alloc = [&](size_t bytes) {
        char* r = p;
        p += (bytes + 255) & ~(size_t)255;
        return r;
    };
    int* counts  = (int*)alloc((size_t)N * 4);
    int* rs      = (int*)alloc((size_t)(N + 1) * 4);
    int* cursor  = (int*)alloc((size_t)N * 4);
    int* csr     = (int*)alloc((size_t)E * 4);
    int* gstart  = (int*)alloc((size_t)(NG + 1) * 4);
    int* bsum    = (int*)alloc((size_t)NB * 4);
    int* boff    = (int*)alloc((size_t)NB * 4);
    const size_t WSPLIT = 3 * 32768;
    unsigned short* wAhi = (unsigned short*)alloc(WSPLIT * 2);
    unsigned short* wAlo = (unsigned short*)alloc(WSPLIT * 2);
    const size_t NF = (size_t)N * F;
    unsigned short* xhi  = (unsigned short*)alloc(NF * 2);  // doubles as h2hi
    unsigned short* xlo  = (unsigned short*)alloc(NF * 2);  // doubles as h2lo
    unsigned short* H0hi = (unsigned short*)alloc(NF * 2);  // h1 / h3
    unsigned short* H0lo = (unsigned short*)alloc(NF * 2);
    unsigned short* Agghi= (unsigned short*)alloc(NF * 2);  // layer-4 agg only
    float* ps1   = (float*)alloc((size_t)NG * F * 4);
    float* ps2   = (float*)alloc((size_t)NG * F * 4);

    // Prep (independent of CSR chain)
    k_wprep3<<<dim3(384), dim3(256), 0, stream>>>(W1l, W1r, W2l, W2r, W3l, W3r, wAhi, wAlo);
    k_xprep<<<dim3((int)(NF / 4 + 255) / 256, 1, 1), dim3(256), 0, stream>>>(
        (const float4*)x, xhi, xlo, (int)(NF / 4));

    // CSR + graph bounds (rebuilt every call; no static state)
    hipMemsetAsync(counts, 0, (size_t)N * 4, stream);
    k_hist<<<dim3(EB), dim3(256), 0, stream>>>(dst, counts, E);
    k_bsum<<<dim3(NB), dim3(256), 0, stream>>>(counts, bsum, N);
    k_scanb<<<dim3(1), dim3(256), 0, stream>>>(bsum, boff, NB, rs, N);
    k_apply<<<dim3(NB), dim3(256), 0, stream>>>(counts, boff, rs, cursor, N);
    k_scatter<<<dim3(EB), dim3(256), 0, stream>>>(src, dst, cursor, csr, E);
    k_gbounds<<<dim3((NG + 256) / 256), dim3(256), 0, stream>>>(batch, gstart, N, NG);

    const int gemmgrid = (N + 63) / 64;
    const int agggrid  = (N + 15) / 16;

    // Layer 1: h1 = relu([mean(x_nbr)|x]@W1 + b1)  -> H0 (hi+lo)
    k_sage<0><<<dim3(gemmgrid), dim3(256), 0, stream>>>(
        xhi, xlo, rs, csr, wAhi + 0 * 32768, wAlo + 0 * 32768, b1, H0hi, H0lo, N);
    // Layer 2: h2 -> xhi/xlo (x dead after layer 1)
    k_sage<0><<<dim3(gemmgrid), dim3(256), 0, stream>>>(
        H0hi, H0lo, rs, csr, wAhi + 1 * 32768, wAlo + 1 * 32768, b2, xhi, xlo, N);
    // Layer 3: h3 -> H0 (hi only; lo never consumed)
    k_sage<1><<<dim3(gemmgrid), dim3(256), 0, stream>>>(
        xhi, xlo, rs, csr, wAhi + 2 * 32768, wAlo + 2 * 32768, b3, H0hi, nullptr, N);
    // Layer 4 (pooled): Agg = mean(h3_nbr) (hi only); pool; tiny GEMM
    k_aggm_bf<0><<<dim3(agggrid), dim3(256), 0, stream>>>(H0hi, rs, csr, Agghi, nullptr, N);
    k_pool<<<dim3(NG), dim3(F), 0, stream>>>(Agghi, H0hi, gstart, ps1, ps2);
    k_final<<<dim3(NG / 4), dim3(256), 0, stream>>>(ps1, ps2, W4l, W4r, b4, out, NG);
}

// Round 9
// 377.612 us; speedup vs baseline: 1.1485x; 1.1485x over previous
//
#include <hip/hip_runtime.h>

#define F 128
#define NGRAPH 512

typedef __attribute__((ext_vector_type(8))) __bf16 bf16x8;
typedef __attribute__((ext_vector_type(4))) float f32x4;
typedef __attribute__((ext_vector_type(8))) unsigned short u16x8;

// ---- bf16 helpers (RTNE) ----
__device__ __forceinline__ unsigned short f2bf(float f) {
    unsigned int u = __float_as_uint(f);
    u = (u + 0x7fffu + ((u >> 16) & 1u)) >> 16;
    return (unsigned short)u;
}
__device__ __forceinline__ float bf2f(unsigned short b) {
    return __uint_as_float(((unsigned int)b) << 16);
}

// ---------------- CSR build ----------------

__global__ __launch_bounds__(256) void k_hist(const int* __restrict__ dst,
                                              int* __restrict__ counts, int e) {
    int i = blockIdx.x * 256 + threadIdx.x;
    if (i < e) atomicAdd(&counts[dst[i]], 1);
}

__global__ __launch_bounds__(256) void k_bsum(const int* __restrict__ counts,
                                              int* __restrict__ bsum, int n) {
    __shared__ int sm[256];
    const int t = threadIdx.x;
    int i = blockIdx.x * 256 + t;
    sm[t] = (i < n) ? counts[i] : 0;
    __syncthreads();
    for (int off = 128; off > 0; off >>= 1) {
        if (t < off) sm[t] += sm[t + off];
        __syncthreads();
    }
    if (t == 0) bsum[blockIdx.x] = sm[0];
}

__global__ __launch_bounds__(256) void k_scanb(const int* __restrict__ bsum,
                                               int* __restrict__ boff, int nb,
                                               int* __restrict__ rs, int n) {
    __shared__ int sm[256];
    const int t = threadIdx.x;
    const int npt = (nb + 255) >> 8;
    const int base = t * npt;
    int s = 0;
    for (int i = 0; i < npt; i++) { int idx = base + i; if (idx < nb) s += bsum[idx]; }
    sm[t] = s;
    __syncthreads();
    for (int off = 1; off < 256; off <<= 1) {
        int u = (t >= off) ? sm[t - off] : 0;
        __syncthreads();
        sm[t] += u;
        __syncthreads();
    }
    int run = (t == 0) ? 0 : sm[t - 1];
    for (int i = 0; i < npt; i++) {
        int idx = base + i;
        if (idx < nb) { boff[idx] = run; run += bsum[idx]; }
    }
    if (t == 255) rs[n] = sm[255];
}

__global__ __launch_bounds__(256) void k_apply(const int* __restrict__ counts,
                                               const int* __restrict__ boff,
                                               int* __restrict__ rs,
                                               int* __restrict__ cursor, int n) {
    __shared__ int sm[256];
    const int t = threadIdx.x;
    int i = blockIdx.x * 256 + t;
    int v = (i < n) ? counts[i] : 0;
    sm[t] = v;
    __syncthreads();
    for (int off = 1; off < 256; off <<= 1) {
        int u = (t >= off) ? sm[t - off] : 0;
        __syncthreads();
        sm[t] += u;
        __syncthreads();
    }
    int excl = sm[t] - v + boff[blockIdx.x];
    if (i < n) { rs[i] = excl; cursor[i] = excl; }
}

__global__ __launch_bounds__(256) void k_scatter(const int* __restrict__ src,
                                                 const int* __restrict__ dst,
                                                 int* __restrict__ cursor,
                                                 int* __restrict__ csr, int e) {
    int i = blockIdx.x * 256 + threadIdx.x;
    if (i < e) {
        int p = atomicAdd(&cursor[dst[i]], 1);
        csr[p] = src[i];
    }
}

__global__ void k_gbounds(const int* __restrict__ batch, int* __restrict__ gstart,
                          int n, int ng) {
    int g = blockIdx.x * blockDim.x + threadIdx.x;
    if (g > ng) return;
    if (g == ng) { gstart[ng] = n; return; }
    int lo = 0, hi = n;
    while (lo < hi) {
        int mid = (lo + hi) >> 1;
        if (batch[mid] < g) lo = mid + 1; else hi = mid;
    }
    gstart[g] = lo;
}

// ---------------- weight prep: 3 layers, fp32 -> bf16 hi/lo, frag-major ----------------

__global__ __launch_bounds__(256) void k_wprep3(
    const float* __restrict__ W1l, const float* __restrict__ W1r,
    const float* __restrict__ W2l, const float* __restrict__ W2r,
    const float* __restrict__ W3l, const float* __restrict__ W3r,
    unsigned short* __restrict__ whi, unsigned short* __restrict__ wlo) {
    int tid = blockIdx.x * 256 + threadIdx.x;   // 0 .. 98303
    if (tid >= 3 * 32768) return;
    int layer = tid >> 15;
    int t = tid & 32767;
    const float* Wl = (layer == 0) ? W1l : ((layer == 1) ? W2l : W3l);
    const float* Wr = (layer == 0) ? W1r : ((layer == 1) ? W2r : W3r);
    int j = t & 7;
    int fp = t >> 3;
    int l = fp & 63;
    int ks = (fp >> 6) & 7;
    int nt = fp >> 9;
    int k = ks * 32 + ((l >> 4) << 3) + j;
    int n = nt * 16 + (l & 15);
    float v = (k < F) ? Wl[k * F + n] : Wr[(k - F) * F + n];
    unsigned short hi = f2bf(v);
    unsigned short lo = f2bf(v - bf2f(hi));
    whi[tid] = hi;
    wlo[tid] = lo;
}

// ---------------- x prep: fp32 -> bf16 hi/lo ----------------

__global__ __launch_bounds__(256) void k_xprep(const float4* __restrict__ x4,
                                               unsigned short* __restrict__ hi,
                                               unsigned short* __restrict__ lo, int n4) {
    int i = blockIdx.x * 256 + threadIdx.x;
    if (i >= n4) return;
    float4 v = x4[i];
    ushort4 h, l;
    h.x = f2bf(v.x); l.x = f2bf(v.x - bf2f(h.x));
    h.y = f2bf(v.y); l.y = f2bf(v.y - bf2f(h.y));
    h.z = f2bf(v.z); l.z = f2bf(v.z - bf2f(h.z));
    h.w = f2bf(v.w); l.w = f2bf(v.w - bf2f(h.w));
    *(ushort4*)&hi[i * 4] = h;
    *(ushort4*)&lo[i * 4] = l;
}

// ---------------- aggregation (bf16 gather): agg[v] = mean_e h[csr[e]] ----------------
// 16 lanes per node (u16x8 = 16B each), 16 nodes per 256-block; fp32 accumulate;
// epilogue splits mean into bf16 hi/lo.

__global__ __launch_bounds__(256) void k_aggm_bf(
    const unsigned short* __restrict__ hbf, const int* __restrict__ rs,
    const int* __restrict__ csr,
    unsigned short* __restrict__ agghi, unsigned short* __restrict__ agglo, int nnodes)
{
    int v = blockIdx.x * 16 + (threadIdx.x >> 4);
    if (v >= nnodes) return;
    int c = threadIdx.x & 15;
    const u16x8* h8 = (const u16x8*)hbf;
    int e0 = rs[v], e1 = rs[v + 1];

    float s0[8] = {}, s1[8] = {}, s2[8] = {}, s3[8] = {};
    int e = e0;
    for (; e + 4 <= e1; e += 4) {
        int a = csr[e], b = csr[e + 1], c2 = csr[e + 2], d = csr[e + 3];
        u16x8 va = h8[a * 16 + c];
        u16x8 vb = h8[b * 16 + c];
        u16x8 vc = h8[c2 * 16 + c];
        u16x8 vd = h8[d * 16 + c];
#pragma unroll
        for (int j = 0; j < 8; j++) {
            s0[j] += bf2f(va[j]);
            s1[j] += bf2f(vb[j]);
            s2[j] += bf2f(vc[j]);
            s3[j] += bf2f(vd[j]);
        }
    }
    for (; e < e1; e++) {
        u16x8 va = h8[csr[e] * 16 + c];
#pragma unroll
        for (int j = 0; j < 8; j++) s0[j] += bf2f(va[j]);
    }
    const float inv = 1.f / (float)max(e1 - e0, 1);
    u16x8 hi8, lo8;
#pragma unroll
    for (int j = 0; j < 8; j++) {
        float m = (s0[j] + s1[j] + s2[j] + s3[j]) * inv;
        unsigned short h = f2bf(m);
        hi8[j] = h;
        lo8[j] = f2bf(m - bf2f(h));
    }
    ((u16x8*)agghi)[v * 16 + c] = hi8;
    ((u16x8*)agglo)[v * 16 + c] = lo8;
}

// ---------------- fused MFMA GEMM: C = relu([Agg|H] @ [Wl;Wr] + bias), bf16 in/out ----
// K = 256; split-bf16 3-pass: Ahi@Whi + Ahi@Wlo + Alo@Whi.
// Block: 256 threads (4 waves), 64 rows x 128 cols. Wave w: col-tiles {2w,2w+1}.
// LDS hi/lo tiles XOR-swizzled at 8-elem grain: idx ^= (row&7)<<3.
// NOLO=1 skips the C-lo store (layer 3: lo never consumed downstream).

template <int NOLO>
__global__ __launch_bounds__(256, 2) void k_gemm_fused(
    const unsigned short* __restrict__ Ahi, const unsigned short* __restrict__ Alo,
    const unsigned short* __restrict__ Bhi, const unsigned short* __restrict__ Blo,
    const unsigned short* __restrict__ whi, const unsigned short* __restrict__ wlo,
    const float* __restrict__ bias,
    unsigned short* __restrict__ Chi, unsigned short* __restrict__ Clo, int nrows)
{
    __shared__ unsigned short ahi[64 * 256];
    __shared__ unsigned short alo[64 * 256];
    const int t = threadIdx.x;
    const int row0 = blockIdx.x * 64;

    // ---- stage 64 rows x 256 k (bf16 copies, no conversion) ----
    {
        const u16x8* A8h = (const u16x8*)Ahi;
        const u16x8* A8l = (const u16x8*)Alo;
        const u16x8* B8h = (const u16x8*)Bhi;
        const u16x8* B8l = (const u16x8*)Blo;
        u16x8 z8 = (u16x8)0;
#pragma unroll
        for (int it = 0; it < 8; it++) {
            int i = t + 256 * it;          // 0..2047
            int row = i >> 5;              // 0..63
            int c8 = i & 31;               // u16x8 chunk within 256 k
            bool ok = (row0 + row) < nrows;
            const u16x8* ph = (c8 < 16) ? A8h : B8h;
            const u16x8* pl = (c8 < 16) ? A8l : B8l;
            int si = (row0 + row) * 16 + (c8 & 15);
            u16x8 vh = ok ? ph[si] : z8;
            u16x8 vl = ok ? pl[si] : z8;
            int didx = row * 256 + ((c8 * 8) ^ ((row & 7) << 3));
            *(u16x8*)&ahi[didx] = vh;
            *(u16x8*)&alo[didx] = vl;
        }
    }
    __syncthreads();

    const int w = t >> 6;
    const int l = t & 63;
    const int lm = l & 15;
    const int lk = l >> 4;
    const bf16x8* whiv = (const bf16x8*)whi;
    const bf16x8* wlov = (const bf16x8*)wlo;

    f32x4 acc[4][2];
#pragma unroll
    for (int rt = 0; rt < 4; rt++)
#pragma unroll
        for (int j = 0; j < 2; j++) acc[rt][j] = (f32x4)(0.f);

    for (int ks = 0; ks < 8; ks++) {
        const int kidx = ks * 32 + lk * 8;
        bf16x8 ah[4], al[4];
#pragma unroll
        for (int rt = 0; rt < 4; rt++) {
            int row = rt * 16 + lm;
            int idx = row * 256 + (kidx ^ ((row & 7) << 3));
            ah[rt] = *(const bf16x8*)&ahi[idx];
            al[rt] = *(const bf16x8*)&alo[idx];
        }
#pragma unroll
        for (int j = 0; j < 2; j++) {
            int nt = 2 * w + j;
            bf16x8 wh = whiv[(nt * 8 + ks) * 64 + l];
            bf16x8 wl = wlov[(nt * 8 + ks) * 64 + l];
#pragma unroll
            for (int rt = 0; rt < 4; rt++) {
                acc[rt][j] = __builtin_amdgcn_mfma_f32_16x16x32_bf16(ah[rt], wh, acc[rt][j], 0, 0, 0);
                acc[rt][j] = __builtin_amdgcn_mfma_f32_16x16x32_bf16(ah[rt], wl, acc[rt][j], 0, 0, 0);
                acc[rt][j] = __builtin_amdgcn_mfma_f32_16x16x32_bf16(al[rt], wh, acc[rt][j], 0, 0, 0);
            }
        }
    }

    // ---- epilogue: + bias, relu, split bf16 hi/lo, store ----
#pragma unroll
    for (int j = 0; j < 2; j++) {
        int col = (2 * w + j) * 16 + lm;
        float bv = bias[col];
#pragma unroll
        for (int rt = 0; rt < 4; rt++) {
#pragma unroll
            for (int r = 0; r < 4; r++) {
                int row = row0 + rt * 16 + lk * 4 + r;
                if (row < nrows) {
                    float v = fmaxf(acc[rt][j][r] + bv, 0.f);
                    unsigned short h = f2bf(v);
                    Chi[(size_t)row * F + col] = h;
                    if (!NOLO) Clo[(size_t)row * F + col] = f2bf(v - bf2f(h));
                }
            }
        }
    }
}

// ---------------- layer 4 fused: per-graph pool of agg4 and h3 ----------------
// One block per graph (batch sorted -> contiguous node ranges).
// 512 threads = 32 groups x 16 lanes; lane c covers channels [8c, 8c+8).
// ps1[g] = mean_v mean_nbr(h3);  ps2[g] = mean_v h3[v].  fp32 accumulate throughout.

__global__ __launch_bounds__(512) void k_gpool(
    const unsigned short* __restrict__ h3hi, const int* __restrict__ rs,
    const int* __restrict__ csr, const int* __restrict__ gstart,
    float* __restrict__ ps1, float* __restrict__ ps2)
{
    __shared__ float a1[32][F];
    __shared__ float a2[32][F];
    const int g = blockIdx.x;
    const int v0 = gstart[g], v1 = gstart[g + 1];
    const int grp = threadIdx.x >> 4;   // 0..31
    const int c = threadIdx.x & 15;
    const u16x8* h8 = (const u16x8*)h3hi;

    float l1[8] = {}, l2[8] = {};
    for (int v = v0 + grp; v < v1; v += 32) {
        int e0 = rs[v], e1 = rs[v + 1];
        float s0[8] = {}, s1[8] = {}, s2[8] = {}, s3[8] = {};
        int e = e0;
        for (; e + 4 <= e1; e += 4) {
            int a = csr[e], b = csr[e + 1], c2 = csr[e + 2], d = csr[e + 3];
            u16x8 va = h8[a * 16 + c];
            u16x8 vb = h8[b * 16 + c];
            u16x8 vc = h8[c2 * 16 + c];
            u16x8 vd = h8[d * 16 + c];
#pragma unroll
            for (int j = 0; j < 8; j++) {
                s0[j] += bf2f(va[j]);
                s1[j] += bf2f(vb[j]);
                s2[j] += bf2f(vc[j]);
                s3[j] += bf2f(vd[j]);
            }
        }
        for (; e < e1; e++) {
            u16x8 va = h8[csr[e] * 16 + c];
#pragma unroll
            for (int j = 0; j < 8; j++) s0[j] += bf2f(va[j]);
        }
        const float invd = 1.f / (float)max(e1 - e0, 1);
        u16x8 sv = h8[v * 16 + c];
#pragma unroll
        for (int j = 0; j < 8; j++) {
            l1[j] += (s0[j] + s1[j] + s2[j] + s3[j]) * invd;
            l2[j] += bf2f(sv[j]);
        }
    }
#pragma unroll
    for (int j = 0; j < 8; j++) {
        a1[grp][c * 8 + j] = l1[j];
        a2[grp][c * 8 + j] = l2[j];
    }
    __syncthreads();
    for (int off = 16; off > 0; off >>= 1) {
        if (grp < off) {
#pragma unroll
            for (int j = 0; j < 8; j++) {
                a1[grp][c * 8 + j] += a1[grp + off][c * 8 + j];
                a2[grp][c * 8 + j] += a2[grp + off][c * 8 + j];
            }
        }
        __syncthreads();
    }
    if (grp == 0) {
        const float inv = 1.f / (float)max(v1 - v0, 1);
#pragma unroll
        for (int j = 0; j < 8; j++) {
            ps1[g * F + c * 8 + j] = a1[0][c * 8 + j] * inv;
            ps2[g * F + c * 8 + j] = a2[0][c * 8 + j] * inv;
        }
    }
}

// ---------------- final tiny GEMM ----------------

__global__ void k_final(const float* __restrict__ ps1, const float* __restrict__ ps2,
                        const float* __restrict__ W4l, const float* __restrict__ W4r,
                        const float* __restrict__ b4, float* __restrict__ out, int ngraph)
{
    int g = blockIdx.x * 4 + (threadIdx.x >> 6);
    int lane = threadIdx.x & 63;
    if (g >= ngraph) return;
    int k0 = lane * 2;
    float a0 = ps1[g * F + k0], a1 = ps1[g * F + k0 + 1];
    float c0v = ps2[g * F + k0], c1v = ps2[g * F + k0 + 1];
    float p0 = a0 * W4l[k0 * 2 + 0] + a1 * W4l[(k0 + 1) * 2 + 0] +
               c0v * W4r[k0 * 2 + 0] + c1v * W4r[(k0 + 1) * 2 + 0];
    float p1 = a0 * W4l[k0 * 2 + 1] + a1 * W4l[(k0 + 1) * 2 + 1] +
               c0v * W4r[k0 * 2 + 1] + c1v * W4r[(k0 + 1) * 2 + 1];
#pragma unroll
    for (int off = 32; off > 0; off >>= 1) {
        p0 += __shfl_down(p0, off);
        p1 += __shfl_down(p1, off);
    }
    if (lane == 0) {
        out[g * 2 + 0] = p0 + b4[0];
        out[g * 2 + 1] = p1 + b4[1];
    }
}

// ---------------- launcher ----------------

extern "C" void kernel_launch(void* const* d_in, const int* in_sizes, int n_in,
                              void* d_out, int out_size, void* d_ws, size_t ws_size,
                              hipStream_t stream)
{
    (void)n_in; (void)out_size; (void)ws_size;
    const float* x    = (const float*)d_in[0];
    const int*   ei   = (const int*)d_in[1];
    const int*   batch= (const int*)d_in[2];
    const float* W1l = (const float*)d_in[3];
    const float* W1r = (const float*)d_in[4];
    const float* b1  = (const float*)d_in[5];
    const float* W2l = (const float*)d_in[6];
    const float* W2r = (const float*)d_in[7];
    const float* b2  = (const float*)d_in[8];
    const float* W3l = (const float*)d_in[9];
    const float* W3r = (const float*)d_in[10];
    const float* b3  = (const float*)d_in[11];
    const float* W4l = (const float*)d_in[12];
    const float* W4r = (const float*)d_in[13];
    const float* b4  = (const float*)d_in[14];
    float* out = (float*)d_out;

    const int N = in_sizes[0] / F;   // 50000
    const int E = in_sizes[1] / 2;   // 600000
    const int NG = NGRAPH;
    const int* src = ei;
    const int* dst = ei + E;
    const int NB = (N + 255) / 256;
    const int EB = (E + 255) / 256;

    char* p = (char*)d_ws;
    auto alloc = [&](size_t bytes) {
        char* r = p;
        p += (bytes + 255) & ~(size_t)255;
        return r;
    };
    int* counts  = (int*)alloc((size_t)N * 4);
    int* rs      = (int*)alloc((size_t)(N + 1) * 4);
    int* cursor  = (int*)alloc((size_t)N * 4);
    int* csr     = (int*)alloc((size_t)E * 4);
    int* gstart  = (int*)alloc((size_t)(NG + 1) * 4);
    int* bsum    = (int*)alloc((size_t)NB * 4);
    int* boff    = (int*)alloc((size_t)NB * 4);
    const size_t WSPLIT = 3 * 32768;
    unsigned short* wAhi = (unsigned short*)alloc(WSPLIT * 2);
    unsigned short* wAlo = (unsigned short*)alloc(WSPLIT * 2);
    const size_t NF = (size_t)N * F;
    unsigned short* xhi  = (unsigned short*)alloc(NF * 2);  // doubles as h2hi
    unsigned short* xlo  = (unsigned short*)alloc(NF * 2);  // doubles as h2lo
    unsigned short* H0hi = (unsigned short*)alloc(NF * 2);  // h1 / h3
    unsigned short* H0lo = (unsigned short*)alloc(NF * 2);
    unsigned short* Agghi= (unsigned short*)alloc(NF * 2);
    unsigned short* Agglo= (unsigned short*)alloc(NF * 2);
    float* ps1   = (float*)alloc((size_t)NG * F * 4);
    float* ps2   = (float*)alloc((size_t)NG * F * 4);

    // Prep (independent of CSR chain)
    k_wprep3<<<dim3(384), dim3(256), 0, stream>>>(W1l, W1r, W2l, W2r, W3l, W3r, wAhi, wAlo);
    k_xprep<<<dim3((int)(NF / 4 + 255) / 256, 1, 1), dim3(256), 0, stream>>>(
        (const float4*)x, xhi, xlo, (int)(NF / 4));

    // CSR + graph bounds (rebuilt every call; no static state)
    hipMemsetAsync(counts, 0, (size_t)N * 4, stream);
    k_hist<<<dim3(EB), dim3(256), 0, stream>>>(dst, counts, E);
    k_bsum<<<dim3(NB), dim3(256), 0, stream>>>(counts, bsum, N);
    k_scanb<<<dim3(1), dim3(256), 0, stream>>>(bsum, boff, NB, rs, N);
    k_apply<<<dim3(NB), dim3(256), 0, stream>>>(counts, boff, rs, cursor, N);
    k_scatter<<<dim3(EB), dim3(256), 0, stream>>>(src, dst, cursor, csr, E);
    k_gbounds<<<dim3((NG + 256) / 256), dim3(256), 0, stream>>>(batch, gstart, N, NG);

    const int gemmgrid = (N + 63) / 64;
    const int agggrid  = (N + 15) / 16;

    // Layer 1: Agg = mean(x_nbr); h1 = relu(Agg@W1l + x@W1r + b1)  -> H0 (hi+lo)
    k_aggm_bf<<<dim3(agggrid), dim3(256), 0, stream>>>(xhi, rs, csr, Agghi, Agglo, N);
    k_gemm_fused<0><<<dim3(gemmgrid), dim3(256), 0, stream>>>(
        Agghi, Agglo, xhi, xlo, wAhi + 0 * 32768, wAlo + 0 * 32768, b1, H0hi, H0lo, N);
    // Layer 2: h2 -> xhi/xlo (x dead after layer 1)
    k_aggm_bf<<<dim3(agggrid), dim3(256), 0, stream>>>(H0hi, rs, csr, Agghi, Agglo, N);
    k_gemm_fused<0><<<dim3(gemmgrid), dim3(256), 0, stream>>>(
        Agghi, Agglo, H0hi, H0lo, wAhi + 1 * 32768, wAlo + 1 * 32768, b2, xhi, xlo, N);
    // Layer 3: h3 -> H0 (hi only; lo never consumed)
    k_aggm_bf<<<dim3(agggrid), dim3(256), 0, stream>>>(xhi, rs, csr, Agghi, Agglo, N);
    k_gemm_fused<1><<<dim3(gemmgrid), dim3(256), 0, stream>>>(
        Agghi, Agglo, xhi, xlo, wAhi + 2 * 32768, wAlo + 2 * 32768, b3, H0hi, nullptr, N);
    // Layer 4 (fused agg+pool per graph) + final tiny GEMM
    k_gpool<<<dim3(NG), dim3(512), 0, stream>>>(H0hi, rs, csr, gstart, ps1, ps2);
    k_final<<<dim3(NG / 4), dim3(256), 0, stream>>>(ps1, ps2, W4l, W4r, b4, out, NG);
}

// Round 11
// 318.989 us; speedup vs baseline: 1.3595x; 1.1838x over previous
//
#include <hip/hip_runtime.h>

#define F 128
#define NGRAPH 512

typedef __attribute__((ext_vector_type(8))) __bf16 bf16x8;
typedef __attribute__((ext_vector_type(4))) float f32x4;
typedef __attribute__((ext_vector_type(8))) unsigned short u16x8;

// ---- bf16 helpers (RTNE) ----
__device__ __forceinline__ unsigned short f2bf(float f) {
    unsigned int u = __float_as_uint(f);
    u = (u + 0x7fffu + ((u >> 16) & 1u)) >> 16;
    return (unsigned short)u;
}
__device__ __forceinline__ float bf2f(unsigned short b) {
    return __uint_as_float(((unsigned int)b) << 16);
}

// ---------------- CSR build ----------------

// hist + graph-bounds fused: blocks [0,EB) histogram; blocks [EB,EB+3) binary-search gstart.
__global__ __launch_bounds__(256) void k_hist_gb(
    const int* __restrict__ dst, int* __restrict__ counts, int e,
    const int* __restrict__ batch, int* __restrict__ gstart, int n, int ng) {
    const int EB = (e + 255) >> 8;
    const int b = blockIdx.x;
    if (b < EB) {
        int i = b * 256 + threadIdx.x;
        if (i < e) atomicAdd(&counts[dst[i]], 1);
    } else {
        int g = (b - EB) * 256 + threadIdx.x;
        if (g > ng) return;
        if (g == ng) { gstart[ng] = n; return; }
        int lo = 0, hi = n;
        while (lo < hi) {
            int mid = (lo + hi) >> 1;
            if (batch[mid] < g) lo = mid + 1; else hi = mid;
        }
        gstart[g] = lo;
    }
}

__global__ __launch_bounds__(256) void k_bsum(const int* __restrict__ counts,
                                              int* __restrict__ bsum, int n) {
    __shared__ int sm[256];
    const int t = threadIdx.x;
    int i = blockIdx.x * 256 + t;
    sm[t] = (i < n) ? counts[i] : 0;
    __syncthreads();
    for (int off = 128; off > 0; off >>= 1) {
        if (t < off) sm[t] += sm[t + off];
        __syncthreads();
    }
    if (t == 0) bsum[blockIdx.x] = sm[0];
}

__global__ __launch_bounds__(256) void k_scanb(const int* __restrict__ bsum,
                                               int* __restrict__ boff, int nb,
                                               int* __restrict__ rs, int n) {
    __shared__ int sm[256];
    const int t = threadIdx.x;
    const int npt = (nb + 255) >> 8;
    const int base = t * npt;
    int s = 0;
    for (int i = 0; i < npt; i++) { int idx = base + i; if (idx < nb) s += bsum[idx]; }
    sm[t] = s;
    __syncthreads();
    for (int off = 1; off < 256; off <<= 1) {
        int u = (t >= off) ? sm[t - off] : 0;
        __syncthreads();
        sm[t] += u;
        __syncthreads();
    }
    int run = (t == 0) ? 0 : sm[t - 1];
    for (int i = 0; i < npt; i++) {
        int idx = base + i;
        if (idx < nb) { boff[idx] = run; run += bsum[idx]; }
    }
    if (t == 255) rs[n] = sm[255];
}

__global__ __launch_bounds__(256) void k_apply(const int* __restrict__ counts,
                                               const int* __restrict__ boff,
                                               int* __restrict__ rs,
                                               int* __restrict__ cursor, int n) {
    __shared__ int sm[256];
    const int t = threadIdx.x;
    int i = blockIdx.x * 256 + t;
    int v = (i < n) ? counts[i] : 0;
    sm[t] = v;
    __syncthreads();
    for (int off = 1; off < 256; off <<= 1) {
        int u = (t >= off) ? sm[t - off] : 0;
        __syncthreads();
        sm[t] += u;
        __syncthreads();
    }
    int excl = sm[t] - v + boff[blockIdx.x];
    if (i < n) { rs[i] = excl; cursor[i] = excl; }
}

__global__ __launch_bounds__(256) void k_scatter(const int* __restrict__ src,
                                                 const int* __restrict__ dst,
                                                 int* __restrict__ cursor,
                                                 int* __restrict__ csr, int e) {
    int i = blockIdx.x * 256 + threadIdx.x;
    if (i < e) {
        int p = atomicAdd(&cursor[dst[i]], 1);
        csr[p] = src[i];
    }
}

// ---------------- prep fused: W split (hi/lo frag-major) + x -> bf16 hi ----------------
// blocks [0,384): weights; blocks [384, 384+XB): features.
// W frag-major per layer (32768 u16): ((nt*8+ks)*64 + l)*8 + j holds
//   Wcat[ks*32+(l>>4)*8+j][nt*16+(l&15)],  Wcat = [Wl; Wr] (256 x 128).

__global__ __launch_bounds__(256) void k_prep(
    const float* __restrict__ W1l, const float* __restrict__ W1r,
    const float* __restrict__ W2l, const float* __restrict__ W2r,
    const float* __restrict__ W3l, const float* __restrict__ W3r,
    unsigned short* __restrict__ whi, unsigned short* __restrict__ wlo,
    const float4* __restrict__ x4, unsigned short* __restrict__ xhi, int n4) {
    const int b = blockIdx.x;
    if (b < 384) {
        int tid = b * 256 + threadIdx.x;   // 0 .. 98303
        int layer = tid >> 15;
        int t = tid & 32767;
        const float* Wl = (layer == 0) ? W1l : ((layer == 1) ? W2l : W3l);
        const float* Wr = (layer == 0) ? W1r : ((layer == 1) ? W2r : W3r);
        int j = t & 7;
        int fp = t >> 3;
        int l = fp & 63;
        int ks = (fp >> 6) & 7;
        int nt = fp >> 9;
        int k = ks * 32 + ((l >> 4) << 3) + j;
        int n = nt * 16 + (l & 15);
        float v = (k < F) ? Wl[k * F + n] : Wr[(k - F) * F + n];
        unsigned short hi = f2bf(v);
        unsigned short lo = f2bf(v - bf2f(hi));
        whi[tid] = hi;
        wlo[tid] = lo;
    } else {
        int i = (b - 384) * 256 + threadIdx.x;
        if (i >= n4) return;
        float4 v = x4[i];
        ushort4 h;
        h.x = f2bf(v.x); h.y = f2bf(v.y); h.z = f2bf(v.z); h.w = f2bf(v.w);
        *(ushort4*)&xhi[i * 4] = h;
    }
}

// ---------------- aggregation (bf16 gather): agg[v] = mean_e h[csr[e]], hi only ----

__global__ __launch_bounds__(256) void k_aggm_bf(
    const unsigned short* __restrict__ hbf, const int* __restrict__ rs,
    const int* __restrict__ csr, unsigned short* __restrict__ agghi, int nnodes)
{
    int v = blockIdx.x * 16 + (threadIdx.x >> 4);
    if (v >= nnodes) return;
    int c = threadIdx.x & 15;
    const u16x8* h8 = (const u16x8*)hbf;
    int e0 = rs[v], e1 = rs[v + 1];

    float s0[8] = {}, s1[8] = {}, s2[8] = {}, s3[8] = {};
    int e = e0;
    for (; e + 4 <= e1; e += 4) {
        int a = csr[e], b = csr[e + 1], c2 = csr[e + 2], d = csr[e + 3];
        u16x8 va = h8[a * 16 + c];
        u16x8 vb = h8[b * 16 + c];
        u16x8 vc = h8[c2 * 16 + c];
        u16x8 vd = h8[d * 16 + c];
#pragma unroll
        for (int j = 0; j < 8; j++) {
            s0[j] += bf2f(va[j]);
            s1[j] += bf2f(vb[j]);
            s2[j] += bf2f(vc[j]);
            s3[j] += bf2f(vd[j]);
        }
    }
    for (; e < e1; e++) {
        u16x8 va = h8[csr[e] * 16 + c];
#pragma unroll
        for (int j = 0; j < 8; j++) s0[j] += bf2f(va[j]);
    }
    const float inv = 1.f / (float)max(e1 - e0, 1);
    u16x8 hi8;
#pragma unroll
    for (int j = 0; j < 8; j++)
        hi8[j] = f2bf((s0[j] + s1[j] + s2[j] + s3[j]) * inv);
    ((u16x8*)agghi)[v * 16 + c] = hi8;
}

// ---------------- MFMA GEMM: C = relu([Agg|H] @ [Wl;Wr] + bias) ----------------
// A bf16 (hi only); W split 2-pass: A@Whi + A@Wlo.  K = 256.
// Block: 256 threads (4 waves), 64 rows x 128 cols. Wave w: col-tiles {2w,2w+1}.
// LDS 32KB (single hi tile), XOR-swizzled at 8-elem grain -> 4 blocks/CU.

__global__ __launch_bounds__(256, 4) void k_gemm2(
    const unsigned short* __restrict__ Ahi, const unsigned short* __restrict__ Bhi,
    const unsigned short* __restrict__ whi, const unsigned short* __restrict__ wlo,
    const float* __restrict__ bias, unsigned short* __restrict__ Chi, int nrows)
{
    __shared__ unsigned short ahi[64 * 256];
    const int t = threadIdx.x;
    const int row0 = blockIdx.x * 64;

    // ---- stage 64 rows x 256 k (bf16 copies) ----
    {
        const u16x8* A8h = (const u16x8*)Ahi;
        const u16x8* B8h = (const u16x8*)Bhi;
        u16x8 z8 = (u16x8)0;
#pragma unroll
        for (int it = 0; it < 8; it++) {
            int i = t + 256 * it;          // 0..2047
            int row = i >> 5;              // 0..63
            int c8 = i & 31;               // u16x8 chunk within 256 k
            bool ok = (row0 + row) < nrows;
            const u16x8* ph = (c8 < 16) ? A8h : B8h;
            int si = (row0 + row) * 16 + (c8 & 15);
            u16x8 vh = ok ? ph[si] : z8;
            int didx = row * 256 + ((c8 * 8) ^ ((row & 7) << 3));
            *(u16x8*)&ahi[didx] = vh;
        }
    }
    __syncthreads();

    const int w = t >> 6;
    const int l = t & 63;
    const int lm = l & 15;
    const int lk = l >> 4;
    const bf16x8* whiv = (const bf16x8*)whi;
    const bf16x8* wlov = (const bf16x8*)wlo;

    f32x4 acc[4][2];
#pragma unroll
    for (int rt = 0; rt < 4; rt++)
#pragma unroll
        for (int j = 0; j < 2; j++) acc[rt][j] = (f32x4)(0.f);

    for (int ks = 0; ks < 8; ks++) {
        const int kidx = ks * 32 + lk * 8;
        bf16x8 ah[4];
#pragma unroll
        for (int rt = 0; rt < 4; rt++) {
            int row = rt * 16 + lm;
            int idx = row * 256 + (kidx ^ ((row & 7) << 3));
            ah[rt] = *(const bf16x8*)&ahi[idx];
        }
#pragma unroll
        for (int j = 0; j < 2; j++) {
            int nt = 2 * w + j;
            bf16x8 wh = whiv[(nt * 8 + ks) * 64 + l];
            bf16x8 wl = wlov[(nt * 8 + ks) * 64 + l];
#pragma unroll
            for (int rt = 0; rt < 4; rt++) {
                acc[rt][j] = __builtin_amdgcn_mfma_f32_16x16x32_bf16(ah[rt], wh, acc[rt][j], 0, 0, 0);
                acc[rt][j] = __builtin_amdgcn_mfma_f32_16x16x32_bf16(ah[rt], wl, acc[rt][j], 0, 0, 0);
            }
        }
    }

    // ---- epilogue: + bias, relu, bf16, store ----
#pragma unroll
    for (int j = 0; j < 2; j++) {
        int col = (2 * w + j) * 16 + lm;
        float bv = bias[col];
#pragma unroll
        for (int rt = 0; rt < 4; rt++) {
#pragma unroll
            for (int r = 0; r < 4; r++) {
                int row = row0 + rt * 16 + lk * 4 + r;
                if (row < nrows)
                    Chi[(size_t)row * F + col] = f2bf(fmaxf(acc[rt][j][r] + bv, 0.f));
            }
        }
    }
}

// ---------------- layer 4 fused: per-graph pool of agg4 and h3 ----------------
// One block per graph (batch sorted -> contiguous node ranges).
// 512 threads = 32 groups x 16 lanes; lane c covers channels [8c, 8c+8).
// ps1[g] = mean_v mean_nbr(h3);  ps2[g] = mean_v h3[v].  fp32 accumulate throughout.

__global__ __launch_bounds__(512) void k_gpool(
    const unsigned short* __restrict__ h3hi, const int* __restrict__ rs,
    const int* __restrict__ csr, const int* __restrict__ gstart,
    float* __restrict__ ps1, float* __restrict__ ps2)
{
    __shared__ float a1[32][F];
    __shared__ float a2[32][F];
    const int g = blockIdx.x;
    const int v0 = gstart[g], v1 = gstart[g + 1];
    const int grp = threadIdx.x >> 4;   // 0..31
    const int c = threadIdx.x & 15;
    const u16x8* h8 = (const u16x8*)h3hi;

    float l1[8] = {}, l2[8] = {};
    for (int v = v0 + grp; v < v1; v += 32) {
        int e0 = rs[v], e1 = rs[v + 1];
        float s0[8] = {}, s1[8] = {}, s2[8] = {}, s3[8] = {};
        int e = e0;
        for (; e + 4 <= e1; e += 4) {
            int a = csr[e], b = csr[e + 1], c2 = csr[e + 2], d = csr[e + 3];
            u16x8 va = h8[a * 16 + c];
            u16x8 vb = h8[b * 16 + c];
            u16x8 vc = h8[c2 * 16 + c];
            u16x8 vd = h8[d * 16 + c];
#pragma unroll
            for (int j = 0; j < 8; j++) {
                s0[j] += bf2f(va[j]);
                s1[j] += bf2f(vb[j]);
                s2[j] += bf2f(vc[j]);
                s3[j] += bf2f(vd[j]);
            }
        }
        for (; e < e1; e++) {
            u16x8 va = h8[csr[e] * 16 + c];
#pragma unroll
            for (int j = 0; j < 8; j++) s0[j] += bf2f(va[j]);
        }
        const float invd = 1.f / (float)max(e1 - e0, 1);
        u16x8 sv = h8[v * 16 + c];
#pragma unroll
        for (int j = 0; j < 8; j++) {
            l1[j] += (s0[j] + s1[j] + s2[j] + s3[j]) * invd;
            l2[j] += bf2f(sv[j]);
        }
    }
#pragma unroll
    for (int j = 0; j < 8; j++) {
        a1[grp][c * 8 + j] = l1[j];
        a2[grp][c * 8 + j] = l2[j];
    }
    __syncthreads();
    for (int off = 16; off > 0; off >>= 1) {
        if (grp < off) {
#pragma unroll
            for (int j = 0; j < 8; j++) {
                a1[grp][c * 8 + j] += a1[grp + off][c * 8 + j];
                a2[grp][c * 8 + j] += a2[grp + off][c * 8 + j];
            }
        }
        __syncthreads();
    }
    if (grp == 0) {
        const float inv = 1.f / (float)max(v1 - v0, 1);
#pragma unroll
        for (int j = 0; j < 8; j++) {
            ps1[g * F + c * 8 + j] = a1[0][c * 8 + j] * inv;
            ps2[g * F + c * 8 + j] = a2[0][c * 8 + j] * inv;
        }
    }
}

// ---------------- final tiny GEMM ----------------

__global__ void k_final(const float* __restrict__ ps1, const float* __restrict__ ps2,
                        const float* __restrict__ W4l, const float* __restrict__ W4r,
                        const float* __restrict__ b4, float* __restrict__ out, int ngraph)
{
    int g = blockIdx.x * 4 + (threadIdx.x >> 6);
    int lane = threadIdx.x & 63;
    if (g >= ngraph) return;
    int k0 = lane * 2;
    float a0 = ps1[g * F + k0], a1 = ps1[g * F + k0 + 1];
    float c0v = ps2[g * F + k0], c1v = ps2[g * F + k0 + 1];
    float p0 = a0 * W4l[k0 * 2 + 0] + a1 * W4l[(k0 + 1) * 2 + 0] +
               c0v * W4r[k0 * 2 + 0] + c1v * W4r[(k0 + 1) * 2 + 0];
    float p1 = a0 * W4l[k0 * 2 + 1] + a1 * W4l[(k0 + 1) * 2 + 1] +
               c0v * W4r[k0 * 2 + 1] + c1v * W4r[(k0 + 1) * 2 + 1];
#pragma unroll
    for (int off = 32; off > 0; off >>= 1) {
        p0 += __shfl_down(p0, off);
        p1 += __shfl_down(p1, off);
    }
    if (lane == 0) {
        out[g * 2 + 0] = p0 + b4[0];
        out[g * 2 + 1] = p1 + b4[1];
    }
}

// ---------------- launcher ----------------

extern "C" void kernel_launch(void* const* d_in, const int* in_sizes, int n_in,
                              void* d_out, int out_size, void* d_ws, size_t ws_size,
                              hipStream_t stream)
{
    (void)n_in; (void)out_size; (void)ws_size;
    const float* x    = (const float*)d_in[0];
    const int*   ei   = (const int*)d_in[1];
    const int*   batch= (const int*)d_in[2];
    const float* W1l = (const float*)d_in[3];
    const float* W1r = (const float*)d_in[4];
    const float* b1  = (const float*)d_in[5];
    const float* W2l = (const float*)d_in[6];
    const float* W2r = (const float*)d_in[7];
    const float* b2  = (const float*)d_in[8];
    const float* W3l = (const float*)d_in[9];
    const float* W3r = (const float*)d_in[10];
    const float* b3  = (const float*)d_in[11];
    const float* W4l = (const float*)d_in[12];
    const float* W4r = (const float*)d_in[13];
    const float* b4  = (const float*)d_in[14];
    float* out = (float*)d_out;

    const int N = in_sizes[0] / F;   // 50000
    const int E = in_sizes[1] / 2;   // 600000
    const int NG = NGRAPH;
    const int* src = ei;
    const int* dst = ei + E;
    const int NB = (N + 255) / 256;
    const int EB = (E + 255) / 256;

    char* p = (char*)d_ws;
    auto alloc = [&](size_t bytes) {
        char* r = p;
        p += (bytes + 255) & ~(size_t)255;
        return r;
    };
    int* counts  = (int*)alloc((size_t)N * 4);
    int* rs      = (int*)alloc((size_t)(N + 1) * 4);
    int* cursor  = (int*)alloc((size_t)N * 4);
    int* csr     = (int*)alloc((size_t)E * 4);
    int* gstart  = (int*)alloc((size_t)(NG + 1) * 4);
    int* bsum    = (int*)alloc((size_t)NB * 4);
    int* boff    = (int*)alloc((size_t)NB * 4);
    const size_t WSPLIT = 3 * 32768;
    unsigned short* wAhi = (unsigned short*)alloc(WSPLIT * 2);
    unsigned short* wAlo = (unsigned short*)alloc(WSPLIT * 2);
    const size_t NF = (size_t)N * F;
    unsigned short* xh   = (unsigned short*)alloc(NF * 2);  // x, later h2
    unsigned short* H0h  = (unsigned short*)alloc(NF * 2);  // h1 / h3
    unsigned short* Aggh = (unsigned short*)alloc(NF * 2);
    float* ps1   = (float*)alloc((size_t)NG * F * 4);
    float* ps2   = (float*)alloc((size_t)NG * F * 4);

    const int n4 = (int)(NF / 4);
    const int XB = (n4 + 255) / 256;

    // Prep: W split + x->bf16 (one fused launch, independent of CSR chain)
    k_prep<<<dim3(384 + XB), dim3(256), 0, stream>>>(
        W1l, W1r, W2l, W2r, W3l, W3r, wAhi, wAlo, (const float4*)x, xh, n4);

    // CSR + graph bounds (rebuilt every call; no static state)
    hipMemsetAsync(counts, 0, (size_t)N * 4, stream);
    k_hist_gb<<<dim3(EB + 3), dim3(256), 0, stream>>>(dst, counts, E, batch, gstart, N, NG);
    k_bsum<<<dim3(NB), dim3(256), 0, stream>>>(counts, bsum, N);
    k_scanb<<<dim3(1), dim3(256), 0, stream>>>(bsum, boff, NB, rs, N);
    k_apply<<<dim3(NB), dim3(256), 0, stream>>>(counts, boff, rs, cursor, N);
    k_scatter<<<dim3(EB), dim3(256), 0, stream>>>(src, dst, cursor, csr, E);

    const int gemmgrid = (N + 63) / 64;
    const int agggrid  = (N + 15) / 16;

    // Layer 1: Agg = mean(x_nbr); h1 = relu([Agg|x]@W1 + b1) -> H0
    k_aggm_bf<<<dim3(agggrid), dim3(256), 0, stream>>>(xh, rs, csr, Aggh, N);
    k_gemm2<<<dim3(gemmgrid), dim3(256), 0, stream>>>(
        Aggh, xh, wAhi + 0 * 32768, wAlo + 0 * 32768, b1, H0h, N);
    // Layer 2: h2 -> xh (x dead after layer 1)
    k_aggm_bf<<<dim3(agggrid), dim3(256), 0, stream>>>(H0h, rs, csr, Aggh, N);
    k_gemm2<<<dim3(gemmgrid), dim3(256), 0, stream>>>(
        Aggh, H0h, wAhi + 1 * 32768, wAlo + 1 * 32768, b2, xh, N);
    // Layer 3: h3 -> H0
    k_aggm_bf<<<dim3(agggrid), dim3(256), 0, stream>>>(xh, rs, csr, Aggh, N);
    k_gemm2<<<dim3(gemmgrid), dim3(256), 0, stream>>>(
        Aggh, xh, wAhi + 2 * 32768, wAlo + 2 * 32768, b3, H0h, N);
    // Layer 4 (fused agg+pool per graph) + final tiny GEMM
    k_gpool<<<dim3(NG), dim3(512), 0, stream>>>(H0h, rs, csr, gstart, ps1, ps2);
    k_final<<<dim3(NG / 4), dim3(256), 0, stream>>>(ps1, ps2, W4l, W4r, b4, out, NG);
}